// Round 1
// baseline (154.405 us; speedup 1.0000x reference)
//
#include <hip/hip_runtime.h>
#include <stdint.h>

// LmHead: RMSNorm(8x4096) -> logits = h @ W^T (W: 32000x4096) -> argmax per row.
// Memory-bound: W is 524 MB (> 256 MiB L3) -> HBM stream, floor ~83us @ 6.3 TB/s.

#define D 4096
#define BATCH 8
#define VOCAB 32000
#define VT 8                 // vocab rows per wave-group
#define NGROUPS (VOCAB / VT) // 4000
#define NBLK 512             // kernel B blocks (4 waves each -> 2048 waves)
#define EPS 1e-6f

typedef unsigned long long u64;

// ---------------- Kernel A: RMSNorm -> h in workspace ----------------
__global__ __launch_bounds__(256) void rmsnorm_k(const float* __restrict__ x,
                                                 const float* __restrict__ g,
                                                 float* __restrict__ h) {
    const int b = blockIdx.x;
    const int t = threadIdx.x;
    const int wave = t >> 6, lane = t & 63;
    const float* xr = x + b * D;

    float4 xv[4];
    float s = 0.f;
#pragma unroll
    for (int i = 0; i < 4; ++i) {
        xv[i] = *(const float4*)(xr + i * 1024 + t * 4);
        s += xv[i].x * xv[i].x + xv[i].y * xv[i].y + xv[i].z * xv[i].z + xv[i].w * xv[i].w;
    }
#pragma unroll
    for (int m = 1; m < 64; m <<= 1) s += __shfl_xor(s, m, 64);

    __shared__ float wsum[4];
    if (lane == 0) wsum[wave] = s;
    __syncthreads();
    const float tot = wsum[0] + wsum[1] + wsum[2] + wsum[3];
    const float rs = rsqrtf(tot * (1.f / (float)D) + EPS);

#pragma unroll
    for (int i = 0; i < 4; ++i) {
        const int d = i * 1024 + t * 4;
        const float4 gv = *(const float4*)(g + d);
        float4 o;
        o.x = xv[i].x * rs * gv.x;
        o.y = xv[i].y * rs * gv.y;
        o.z = xv[i].z * rs * gv.z;
        o.w = xv[i].w * rs * gv.w;
        *(float4*)(h + b * D + d) = o;
    }
}

// ------- Kernel B: per-wave 8-row GEMV chunk + running packed argmax -------
__global__ __launch_bounds__(256) void gemv_argmax_k(const float* __restrict__ W,
                                                     const float* __restrict__ h,
                                                     u64* __restrict__ partial) {
    const int lane = threadIdx.x & 63;
    const int wave = threadIdx.x >> 6;
    const int wid = blockIdx.x * 4 + wave;
    const int nw = gridDim.x * 4;

    u64 best = 0ull; // packed (sortable_f32 <<32) | ~idx ; 0 is neutral (no NaNs)

    for (int grp = wid; grp < NGROUPS; grp += nw) {
        const int v0 = grp * VT;
        const float* Wb = W + (size_t)v0 * D;

        float acc[64];
#pragma unroll
        for (int i = 0; i < 64; ++i) acc[i] = 0.f;

#pragma unroll 1
        for (int c = 0; c < 16; ++c) {
            const int d = c * 256 + lane * 4;
            float4 hv[8];
#pragma unroll
            for (int b = 0; b < 8; ++b) hv[b] = *(const float4*)(h + b * D + d);
#pragma unroll
            for (int vi = 0; vi < 8; ++vi) {
                const float4 wv = *(const float4*)(Wb + vi * D + d);
#pragma unroll
                for (int b = 0; b < 8; ++b) {
                    acc[b * 8 + vi] += wv.x * hv[b].x + wv.y * hv[b].y +
                                       wv.z * hv[b].z + wv.w * hv[b].w;
                }
            }
        }

        // Butterfly: reduce 64 values across 64 lanes; lane l ends with total
        // for value index l (j = b*8 + vi). All array indices compile-time.
#pragma unroll
        for (int s = 0; s < 6; ++s) {
            const int m = 1 << s;
            const bool bit = (lane & m) != 0;
#pragma unroll
            for (int u = 0; u < (64 >> (s + 1)); ++u) {
                const float a = acc[2 * u];
                const float c2 = acc[2 * u + 1];
                const float keep = bit ? c2 : a;
                const float send = bit ? a : c2;
                acc[u] = keep + __shfl_xor(send, m, 64);
            }
        }

        const float logit = acc[0];             // logit for b = lane>>3, v = v0 + (lane&7)
        const int vidx = v0 + (lane & 7);
        const uint32_t fb = __float_as_uint(logit);
        const uint32_t key = (fb & 0x80000000u) ? ~fb : (fb | 0x80000000u);
        const u64 pk = ((u64)key << 32) | (uint32_t)(~(uint32_t)vidx);
        best = (pk > best) ? pk : best;
    }

    // merge across the 8 lanes sharing each b (low 3 bits of lane)
#pragma unroll
    for (int m = 1; m <= 4; m <<= 1) {
        const u64 o = __shfl_xor(best, m, 64);
        if (o > best) best = o;
    }

    __shared__ u64 lb[4][8];
    if ((lane & 7) == 0) lb[wave][lane >> 3] = best;
    __syncthreads();
    if (threadIdx.x < 8) {
        const u64 m0 = lb[0][threadIdx.x], m1 = lb[1][threadIdx.x];
        const u64 m2 = lb[2][threadIdx.x], m3 = lb[3][threadIdx.x];
        const u64 a = m0 > m1 ? m0 : m1;
        const u64 b2 = m2 > m3 ? m2 : m3;
        partial[(size_t)blockIdx.x * 8 + threadIdx.x] = a > b2 ? a : b2;
    }
}

// ---------------- Kernel C: final argmax over block partials ----------------
__global__ __launch_bounds__(512) void finalize_k(const u64* __restrict__ partial,
                                                  int* __restrict__ out, int nblk) {
    const int b = threadIdx.x >> 6;   // one wave per batch row
    const int lane = threadIdx.x & 63;
    u64 best = 0ull;
    for (int p = lane; p < nblk; p += 64) {
        const u64 x = partial[(size_t)p * 8 + b];
        if (x > best) best = x;
    }
#pragma unroll
    for (int m = 1; m < 64; m <<= 1) {
        const u64 o = __shfl_xor(best, m, 64);
        if (o > best) best = o;
    }
    if (lane == 0) out[b] = (int)(~(uint32_t)best);
}

extern "C" void kernel_launch(void* const* d_in, const int* in_sizes, int n_in,
                              void* d_out, int out_size, void* d_ws, size_t ws_size,
                              hipStream_t stream) {
    const float* x = (const float*)d_in[0]; // hidden_states [8,4096]
    const float* g = (const float*)d_in[1]; // norm_weight [4096]
    const float* W = (const float*)d_in[2]; // lm_head_weight [32000,4096]
    int* out = (int*)d_out;                 // [8] int32 token ids

    float* h = (float*)d_ws;                                   // 8*4096 f32 = 128 KB
    u64* partial = (u64*)((char*)d_ws + BATCH * D * sizeof(float)); // NBLK*8 u64 = 32 KB

    rmsnorm_k<<<BATCH, 256, 0, stream>>>(x, g, h);
    gemv_argmax_k<<<NBLK, 256, 0, stream>>>(W, h, partial);
    finalize_k<<<1, 512, 0, stream>>>(partial, out, NBLK);
}

// Round 2
// 135.799 us; speedup vs baseline: 1.1370x; 1.1370x over previous
//
#include <hip/hip_runtime.h>
#include <stdint.h>

// LmHead: RMSNorm(8x4096) -> logits = h @ W^T (W: 32000x4096 f32) -> argmax per row.
// Memory-bound: W is 524 MB (> 256 MiB L3) -> pure HBM read stream, floor ~83us.
// R1: 154us = 54% BW. Cause: grid-limited 2 waves/SIMD + per-chunk vmcnt drain.
// R2: VT=4 (acc[32], ~96 VGPR), 8000 waves (1 group each), 2-deep W ping-pong.

#define D 4096
#define BATCH 8
#define VOCAB 32000
#define VT 4                 // vocab rows per wave
#define NGROUPS (VOCAB / VT) // 8000
#define NBLK 2000            // 4 waves/block -> 8000 waves, exactly 1 group per wave
#define EPS 1e-6f

typedef unsigned long long u64;
typedef float f32x4 __attribute__((ext_vector_type(4)));

// ---------------- Kernel A: RMSNorm -> h in workspace ----------------
__global__ __launch_bounds__(256) void rmsnorm_k(const float* __restrict__ x,
                                                 const float* __restrict__ g,
                                                 float* __restrict__ h) {
    const int b = blockIdx.x;
    const int t = threadIdx.x;
    const int wave = t >> 6, lane = t & 63;
    const float* xr = x + b * D;

    f32x4 xv[4];
    float s = 0.f;
#pragma unroll
    for (int i = 0; i < 4; ++i) {
        xv[i] = *(const f32x4*)(xr + i * 1024 + t * 4);
        s += xv[i].x * xv[i].x + xv[i].y * xv[i].y + xv[i].z * xv[i].z + xv[i].w * xv[i].w;
    }
#pragma unroll
    for (int m = 1; m < 64; m <<= 1) s += __shfl_xor(s, m, 64);

    __shared__ float wsum[4];
    if (lane == 0) wsum[wave] = s;
    __syncthreads();
    const float tot = wsum[0] + wsum[1] + wsum[2] + wsum[3];
    const float rs = rsqrtf(tot * (1.f / (float)D) + EPS);

#pragma unroll
    for (int i = 0; i < 4; ++i) {
        const int d = i * 1024 + t * 4;
        const f32x4 gv = *(const f32x4*)(g + d);
        f32x4 o;
        o.x = xv[i].x * rs * gv.x;
        o.y = xv[i].y * rs * gv.y;
        o.z = xv[i].z * rs * gv.z;
        o.w = xv[i].w * rs * gv.w;
        *(f32x4*)(h + b * D + d) = o;
    }
}

// ------- Kernel B: per-wave 4-row GEMV + packed argmax, 2-deep W prefetch -------
__global__ __launch_bounds__(256) void gemv_argmax_k(const float* __restrict__ W,
                                                     const float* __restrict__ h,
                                                     u64* __restrict__ partial) {
    const int lane = threadIdx.x & 63;
    const int wave = threadIdx.x >> 6;
    const int grp = blockIdx.x * 4 + wave;       // [0, 8000)
    const int v0 = grp * VT;
    const float* Wb = W + (size_t)v0 * D;

    float acc[32];
#pragma unroll
    for (int i = 0; i < 32; ++i) acc[i] = 0.f;

    f32x4 bufA[VT], bufB[VT];
    const int dl = lane * 4;

#define LOADW(BUF, c)                                                           \
    {                                                                           \
        const int _d = (c) * 256 + dl;                                          \
        _Pragma("unroll")                                                       \
        for (int vi = 0; vi < VT; ++vi)                                         \
            BUF[vi] = __builtin_nontemporal_load((const f32x4*)(Wb + vi * D + _d)); \
    }

#define COMPUTE(BUF, c)                                                         \
    {                                                                           \
        const int _d = (c) * 256 + dl;                                          \
        _Pragma("unroll")                                                       \
        for (int b = 0; b < 8; ++b) {                                           \
            const f32x4 hv = *(const f32x4*)(h + b * D + _d);                   \
            _Pragma("unroll")                                                   \
            for (int vi = 0; vi < VT; ++vi)                                     \
                acc[b * VT + vi] += BUF[vi].x * hv.x + BUF[vi].y * hv.y +       \
                                    BUF[vi].z * hv.z + BUF[vi].w * hv.w;        \
        }                                                                       \
    }

    LOADW(bufA, 0)
#pragma unroll 1
    for (int c = 0; c < 16; c += 2) {
        LOADW(bufB, c + 1)
        COMPUTE(bufA, c)
        LOADW(bufA, (c + 2 < 16 ? c + 2 : 15))   // last prefetch is a dummy re-read
        COMPUTE(bufB, c + 1)
    }
#undef LOADW
#undef COMPUTE

    // Butterfly: 32 partial dot-products across 64 lanes -> lane l holds total
    // for j = l&31 (b = j>>2, vi = j&3). All indices compile-time.
#pragma unroll
    for (int s = 0; s < 5; ++s) {
        const int m = 1 << s;
        const bool bit = (lane & m) != 0;
#pragma unroll
        for (int u = 0; u < (32 >> (s + 1)); ++u) {
            const float a = acc[2 * u];
            const float c2 = acc[2 * u + 1];
            const float keep = bit ? c2 : a;
            const float send = bit ? a : c2;
            acc[u] = keep + __shfl_xor(send, m, 64);
        }
    }
    float logit = acc[0] + __shfl_xor(acc[0], 32, 64);  // fold duplicate halves

    const int vidx = v0 + (lane & 3);
    const uint32_t fb = __float_as_uint(logit);
    const uint32_t key = (fb & 0x80000000u) ? ~fb : (fb | 0x80000000u);
    u64 best = ((u64)key << 32) | (uint32_t)(~(uint32_t)vidx);

    // merge across vi (bits 0,1) and the duplicate half (bit 5)
#pragma unroll
    for (int m = 1; m <= 2; m <<= 1) {
        const u64 o = __shfl_xor(best, m, 64);
        if (o > best) best = o;
    }
    {
        const u64 o = __shfl_xor(best, 32, 64);
        if (o > best) best = o;
    }

    __shared__ u64 lb[4][8];
    if (lane < 32 && (lane & 3) == 0) lb[wave][lane >> 2] = best;
    __syncthreads();
    if (threadIdx.x < 8) {
        const u64 m0 = lb[0][threadIdx.x], m1 = lb[1][threadIdx.x];
        const u64 m2 = lb[2][threadIdx.x], m3 = lb[3][threadIdx.x];
        const u64 a = m0 > m1 ? m0 : m1;
        const u64 b2 = m2 > m3 ? m2 : m3;
        partial[(size_t)blockIdx.x * 8 + threadIdx.x] = a > b2 ? a : b2;
    }
}

// ---------------- Kernel C: final argmax over block partials ----------------
__global__ __launch_bounds__(512) void finalize_k(const u64* __restrict__ partial,
                                                  int* __restrict__ out, int nblk) {
    const int b = threadIdx.x >> 6;   // one wave per batch row
    const int lane = threadIdx.x & 63;
    u64 best = 0ull;
    for (int p = lane; p < nblk; p += 64) {
        const u64 x = partial[(size_t)p * 8 + b];
        if (x > best) best = x;
    }
#pragma unroll
    for (int m = 1; m < 64; m <<= 1) {
        const u64 o = __shfl_xor(best, m, 64);
        if (o > best) best = o;
    }
    if (lane == 0) out[b] = (int)(~(uint32_t)best);
}

extern "C" void kernel_launch(void* const* d_in, const int* in_sizes, int n_in,
                              void* d_out, int out_size, void* d_ws, size_t ws_size,
                              hipStream_t stream) {
    const float* x = (const float*)d_in[0]; // hidden_states [8,4096]
    const float* g = (const float*)d_in[1]; // norm_weight [4096]
    const float* W = (const float*)d_in[2]; // lm_head_weight [32000,4096]
    int* out = (int*)d_out;                 // [8] int32 token ids

    float* h = (float*)d_ws;                                        // 128 KB
    u64* partial = (u64*)((char*)d_ws + BATCH * D * sizeof(float)); // NBLK*8*8B = 125 KB

    rmsnorm_k<<<BATCH, 256, 0, stream>>>(x, g, h);
    gemv_argmax_k<<<NBLK, 256, 0, stream>>>(W, h, partial);
    finalize_k<<<1, 512, 0, stream>>>(partial, out, NBLK);
}